// Round 13
// baseline (111.317 us; speedup 1.0000x reference)
//
#include <hip/hip_runtime.h>

#define F_ 256
#define S_ 512
#define NH_ 16
#define CCH 32
#define NCH (S_/CCH)
#define KSTR 264   // bf16 row stride for [*][256] LDS tiles
#define TSTR 40    // bf16 row stride for 16x32-ish tiles

typedef __attribute__((ext_vector_type(8))) short short8_t;
typedef __attribute__((ext_vector_type(4))) float f32x4;

// raw barrier: LDS-visibility only; global loads stay in flight (T3/T4)
#define BARX() do { \
  asm volatile("s_waitcnt lgkmcnt(0)" ::: "memory"); \
  __builtin_amdgcn_s_barrier(); \
  __builtin_amdgcn_sched_barrier(0); \
} while (0)

__device__ __forceinline__ float sigmoid_f(float x) { return 1.0f / (1.0f + __expf(-x)); }

__device__ __forceinline__ ushort f2bf(float x) {   // RNE float->bf16
  uint u = __float_as_uint(x);
  u += 0x7FFFu + ((u >> 16) & 1u);
  return (ushort)(u >> 16);
}
__device__ __forceinline__ float bf2f(ushort u) {
  return __uint_as_float((uint)u << 16);
}

template<int CTRL>
__device__ __forceinline__ float dpp_add(float x) {
  int y = __builtin_amdgcn_update_dpp(0, __float_as_int(x), CTRL, 0xf, 0xf, true);
  return x + __int_as_float(y);
}
// butterfly sum over aligned 8-lane groups, result in all 8 lanes
__device__ __forceinline__ float red8(float x) {
  x = dpp_add<0xB1>(x);
  x = dpp_add<0x4E>(x);
  x = dpp_add<0x141>(x);
  return x;
}

// ---------- one-time: weight transpose->bf16 + bias concat ----------
// Wt row layout (ushort offsets): q=0 k=65536 v=131072 e1=196608 a1=212992
//                                 g1=229376 g2=294912 o=360448
__global__ __launch_bounds__(256) void wconv_k(
    const float* __restrict__ Wq, const float* __restrict__ Wk,
    const float* __restrict__ Wv, const float* __restrict__ Wg1,
    const float* __restrict__ Wg2, const float* __restrict__ Wo,
    const float* __restrict__ We1, const float* __restrict__ Wa1,
    const float* __restrict__ be1, const float* __restrict__ ba1,
    ushort* __restrict__ Wt, float* __restrict__ beas)
{
  const int blk = blockIdx.x, tid = threadIdx.x;
  if (blk == 104) {
    if (tid < 64) beas[tid] = be1[tid];
    else if (tid < 128) beas[tid] = ba1[tid - 64];
    return;
  }
  __shared__ float tile[64][65];
  const float* src; int N, k0, n0; size_t dstbase;
  if (blk < 96) {
    const int w = blk >> 4, tl = blk & 15;
    const float* ws_[6] = {Wq, Wk, Wv, Wg1, Wg2, Wo};
    const size_t dstb[6] = {0, 65536, 131072, 229376, 294912, 360448};
    src = ws_[w]; N = 256;
    k0 = (tl >> 2) * 64; n0 = (tl & 3) * 64;
    dstbase = dstb[w];
  } else {
    const int w = (blk - 96) >> 2, tl = (blk - 96) & 3;
    src = w ? Wa1 : We1; N = 64;
    k0 = tl * 64; n0 = 0;
    dstbase = w ? 212992 : 196608;
  }
  #pragma unroll
  for (int p = 0; p < 4; ++p) {
    const int idx = (p << 8) + tid;
    const int r = idx >> 4, c4 = (idx & 15) << 2;
    if (c4 < N) {
      const float4 v = *(const float4*)&src[(size_t)(k0 + r) * N + n0 + c4];
      tile[r][c4 + 0] = v.x; tile[r][c4 + 1] = v.y;
      tile[r][c4 + 2] = v.z; tile[r][c4 + 3] = v.w;
    }
  }
  __syncthreads();
  #pragma unroll
  for (int p = 0; p < 4; ++p) {
    const int idx = (p << 8) + tid;
    const int nl = idx >> 4, kc = (idx & 15) << 2;
    if ((n0 + nl) < ((blk < 96) ? 256 : 64)) {
      ushort4 o;
      o.x = f2bf(tile[kc + 0][nl]); o.y = f2bf(tile[kc + 1][nl]);
      o.z = f2bf(tile[kc + 2][nl]); o.w = f2bf(tile[kc + 3][nl]);
      *(ushort4*)&Wt[dstbase + (size_t)(n0 + nl) * 256 + k0 + kc] = o;
    }
  }
}

// ---------- fused QKVE GEMM: out = f2bf(x) @ [Wq|Wk|Wv|We1|Wa1] ----------
__global__ __launch_bounds__(256) void qkve_k(
    const float* __restrict__ x, const ushort* __restrict__ Wt,
    const float* __restrict__ beas,
    ushort* __restrict__ qb, float* __restrict__ kf,
    ushort* __restrict__ vb, float* __restrict__ sesa)
{
  __shared__ ushort As[2][64 * 72];
  __shared__ ushort Ws[2][64 * 72];
  const int tid = threadIdx.x;
  const int wv = tid >> 6, l = tid & 63;
  const int ln = l & 15, hi = l >> 4, hi4 = hi << 2, hi8 = hi << 3;
  const int wr = wv >> 1, wc = wv & 1;
  const int row0 = blockIdx.y * 64, col0 = blockIdx.x * 64;
  const int r_ = tid >> 3, c8_ = (tid & 7) << 3;

  float4 pAf[4];
  short8_t pB[2];
  auto loadT = [&](int k0) {
    pAf[0] = *(const float4*)&x[(size_t)(row0 + r_) * 256 + k0 + c8_];
    pAf[1] = *(const float4*)&x[(size_t)(row0 + r_) * 256 + k0 + c8_ + 4];
    pAf[2] = *(const float4*)&x[(size_t)(row0 + 32 + r_) * 256 + k0 + c8_];
    pAf[3] = *(const float4*)&x[(size_t)(row0 + 32 + r_) * 256 + k0 + c8_ + 4];
    pB[0] = *(const short8_t*)&Wt[(size_t)(col0 + r_) * 256 + k0 + c8_];
    pB[1] = *(const short8_t*)&Wt[(size_t)(col0 + 32 + r_) * 256 + k0 + c8_];
  };
  auto commitT = [&](int b) {
    #pragma unroll
    for (int h = 0; h < 2; ++h) {
      short8_t s;
      s[0] = (short)f2bf(pAf[h*2].x); s[1] = (short)f2bf(pAf[h*2].y);
      s[2] = (short)f2bf(pAf[h*2].z); s[3] = (short)f2bf(pAf[h*2].w);
      s[4] = (short)f2bf(pAf[h*2+1].x); s[5] = (short)f2bf(pAf[h*2+1].y);
      s[6] = (short)f2bf(pAf[h*2+1].z); s[7] = (short)f2bf(pAf[h*2+1].w);
      *(short8_t*)&As[b][(h * 32 + r_) * 72 + c8_] = s;
    }
    *(short8_t*)&Ws[b][r_ * 72 + c8_] = pB[0];
    *(short8_t*)&Ws[b][(32 + r_) * 72 + c8_] = pB[1];
  };

  f32x4 acc[2][2];
  #pragma unroll
  for (int i = 0; i < 2; ++i)
    #pragma unroll
    for (int j = 0; j < 2; ++j)
      #pragma unroll
      for (int r = 0; r < 4; ++r) acc[i][j][r] = 0.f;

  loadT(0); commitT(0); __syncthreads();
  #pragma unroll
  for (int t = 0; t < 4; ++t) {
    const int b = t & 1;
    if (t < 3) loadT((t + 1) << 6);
    #pragma unroll
    for (int kk = 0; kk < 2; ++kk) {
      short8_t a0 = *(const short8_t*)&As[b][(wr * 32 + ln) * 72 + kk * 32 + hi8];
      short8_t a1 = *(const short8_t*)&As[b][(wr * 32 + 16 + ln) * 72 + kk * 32 + hi8];
      short8_t b0 = *(const short8_t*)&Ws[b][(wc * 32 + ln) * 72 + kk * 32 + hi8];
      short8_t b1 = *(const short8_t*)&Ws[b][(wc * 32 + 16 + ln) * 72 + kk * 32 + hi8];
      acc[0][0] = __builtin_amdgcn_mfma_f32_16x16x32_bf16(a0, b0, acc[0][0], 0, 0, 0);
      acc[0][1] = __builtin_amdgcn_mfma_f32_16x16x32_bf16(a0, b1, acc[0][1], 0, 0, 0);
      acc[1][0] = __builtin_amdgcn_mfma_f32_16x16x32_bf16(a1, b0, acc[1][0], 0, 0, 0);
      acc[1][1] = __builtin_amdgcn_mfma_f32_16x16x32_bf16(a1, b1, acc[1][1], 0, 0, 0);
    }
    if (t < 3) commitT(b ^ 1);
    __syncthreads();
  }

  #pragma unroll
  for (int mi = 0; mi < 2; ++mi)
    #pragma unroll
    for (int ni = 0; ni < 2; ++ni) {
      const int col = col0 + wc * 32 + ni * 16 + ln;
      #pragma unroll
      for (int r = 0; r < 4; ++r) {
        const int row = row0 + wr * 32 + mi * 16 + hi4 + r;
        float vx = acc[mi][ni][r];
        if (col0 < 256)      qb[(size_t)row * 256 + col] = f2bf(vx);
        else if (col0 < 512) kf[(size_t)row * 256 + (col - 256)] = vx;
        else if (col0 < 768) vb[(size_t)row * 256 + (col - 512)] = f2bf(vx);
        else {
          const int cc = col - 768;
          vx += beas[cc];
          vx *= sigmoid_f(vx);
          sesa[(size_t)row * 128 + cc] = vx;
        }
      }
    }
}

// ---------- generic bf16 GEMM (N=256,K=256): C = act(A @ W + bias) ----------
__global__ __launch_bounds__(256) void gemm_bf16_k(
    const ushort* __restrict__ A, const ushort* __restrict__ Wt,
    const float* __restrict__ bias, float* __restrict__ Cf,
    ushort* __restrict__ Cb, int act)
{
  __shared__ ushort As[2][64 * 72];
  __shared__ ushort Ws[2][64 * 72];
  const int tid = threadIdx.x;
  const int wv = tid >> 6, l = tid & 63;
  const int ln = l & 15, hi = l >> 4, hi4 = hi << 2, hi8 = hi << 3;
  const int wr = wv >> 1, wc = wv & 1;
  const int row0 = blockIdx.y * 64, col0 = blockIdx.x * 64;
  const int r_ = tid >> 3, c8_ = (tid & 7) << 3;

  short8_t pA[2], pB[2];
  auto loadT = [&](int k0) {
    pA[0] = *(const short8_t*)&A[(size_t)(row0 + r_) * 256 + k0 + c8_];
    pA[1] = *(const short8_t*)&A[(size_t)(row0 + 32 + r_) * 256 + k0 + c8_];
    pB[0] = *(const short8_t*)&Wt[(size_t)(col0 + r_) * 256 + k0 + c8_];
    pB[1] = *(const short8_t*)&Wt[(size_t)(col0 + 32 + r_) * 256 + k0 + c8_];
  };
  auto commitT = [&](int b) {
    *(short8_t*)&As[b][r_ * 72 + c8_] = pA[0];
    *(short8_t*)&As[b][(32 + r_) * 72 + c8_] = pA[1];
    *(short8_t*)&Ws[b][r_ * 72 + c8_] = pB[0];
    *(short8_t*)&Ws[b][(32 + r_) * 72 + c8_] = pB[1];
  };

  f32x4 acc[2][2];
  #pragma unroll
  for (int i = 0; i < 2; ++i)
    #pragma unroll
    for (int j = 0; j < 2; ++j)
      #pragma unroll
      for (int r = 0; r < 4; ++r) acc[i][j][r] = 0.f;

  loadT(0); commitT(0); __syncthreads();
  #pragma unroll
  for (int t = 0; t < 4; ++t) {
    const int b = t & 1;
    if (t < 3) loadT((t + 1) << 6);
    #pragma unroll
    for (int kk = 0; kk < 2; ++kk) {
      short8_t a0 = *(const short8_t*)&As[b][(wr * 32 + ln) * 72 + kk * 32 + hi8];
      short8_t a1 = *(const short8_t*)&As[b][(wr * 32 + 16 + ln) * 72 + kk * 32 + hi8];
      short8_t b0 = *(const short8_t*)&Ws[b][(wc * 32 + ln) * 72 + kk * 32 + hi8];
      short8_t b1 = *(const short8_t*)&Ws[b][(wc * 32 + 16 + ln) * 72 + kk * 32 + hi8];
      acc[0][0] = __builtin_amdgcn_mfma_f32_16x16x32_bf16(a0, b0, acc[0][0], 0, 0, 0);
      acc[0][1] = __builtin_amdgcn_mfma_f32_16x16x32_bf16(a0, b1, acc[0][1], 0, 0, 0);
      acc[1][0] = __builtin_amdgcn_mfma_f32_16x16x32_bf16(a1, b0, acc[1][0], 0, 0, 0);
      acc[1][1] = __builtin_amdgcn_mfma_f32_16x16x32_bf16(a1, b1, acc[1][1], 0, 0, 0);
    }
    if (t < 3) commitT(b ^ 1);
    __syncthreads();
  }

  #pragma unroll
  for (int mi = 0; mi < 2; ++mi)
    #pragma unroll
    for (int ni = 0; ni < 2; ++ni) {
      const int col = col0 + wc * 32 + ni * 16 + ln;
      const float bval = bias ? bias[col] : 0.f;
      #pragma unroll
      for (int r = 0; r < 4; ++r) {
        const int row = row0 + wr * 32 + mi * 16 + hi4 + r;
        float vx = acc[mi][ni][r] + bval;
        if (act == 1) vx = vx * sigmoid_f(vx);
        if (Cf) Cf[(size_t)row * 256 + col] = vx;
        if (Cb) Cb[(size_t)row * 256 + col] = f2bf(vx);
      }
    }
}

// ---------- fused g1-GEMM (blocks 0..511) + prep (blocks 512..767) ----------
__global__ __launch_bounds__(256) void g1prep_k(
    const ushort* __restrict__ vb, const ushort* __restrict__ WtG1,
    const float* __restrict__ bg1, ushort* __restrict__ t1b,
    const ushort* __restrict__ kb, const ushort* __restrict__ qb,
    const float* __restrict__ eta, const float* __restrict__ alpha,
    ushort* __restrict__ Tg, ushort* __restrict__ Gqg, float* __restrict__ Sg,
    ushort* __restrict__ Ktg)
{
  __shared__ __align__(16) char smem[38592];
  const int blk = blockIdx.x;
  const int tid = threadIdx.x;
  const int l = tid & 63, wv = tid >> 6;
  const int ln = l & 15, hi = l >> 4, hi4 = hi << 2, hi8 = hi << 3;

  if (blk < 512) {
    ushort* As = (ushort*)smem;               // [2][64*72]
    ushort* Ws = (ushort*)(smem + 18432);     // [2][64*72]
    const int wr = wv >> 1, wc = wv & 1;
    const int row0 = (blk >> 2) * 64, col0 = (blk & 3) * 64;
    const int r_ = tid >> 3, c8_ = (tid & 7) << 3;

    short8_t pA[2], pB[2];
    auto loadT = [&](int k0) {
      pA[0] = *(const short8_t*)&vb[(size_t)(row0 + r_) * 256 + k0 + c8_];
      pA[1] = *(const short8_t*)&vb[(size_t)(row0 + 32 + r_) * 256 + k0 + c8_];
      pB[0] = *(const short8_t*)&WtG1[(size_t)(col0 + r_) * 256 + k0 + c8_];
      pB[1] = *(const short8_t*)&WtG1[(size_t)(col0 + 32 + r_) * 256 + k0 + c8_];
    };
    auto commitT = [&](int b) {
      *(short8_t*)&As[b * 4608 + r_ * 72 + c8_] = pA[0];
      *(short8_t*)&As[b * 4608 + (32 + r_) * 72 + c8_] = pA[1];
      *(short8_t*)&Ws[b * 4608 + r_ * 72 + c8_] = pB[0];
      *(short8_t*)&Ws[b * 4608 + (32 + r_) * 72 + c8_] = pB[1];
    };

    f32x4 acc[2][2];
    #pragma unroll
    for (int i = 0; i < 2; ++i)
      #pragma unroll
      for (int j = 0; j < 2; ++j)
        #pragma unroll
        for (int r = 0; r < 4; ++r) acc[i][j][r] = 0.f;

    loadT(0); commitT(0); __syncthreads();
    #pragma unroll
    for (int t = 0; t < 4; ++t) {
      const int b = t & 1;
      if (t < 3) loadT((t + 1) << 6);
      #pragma unroll
      for (int kk = 0; kk < 2; ++kk) {
        short8_t a0 = *(const short8_t*)&As[b * 4608 + (wr * 32 + ln) * 72 + kk * 32 + hi8];
        short8_t a1 = *(const short8_t*)&As[b * 4608 + (wr * 32 + 16 + ln) * 72 + kk * 32 + hi8];
        short8_t b0 = *(const short8_t*)&Ws[b * 4608 + (wc * 32 + ln) * 72 + kk * 32 + hi8];
        short8_t b1 = *(const short8_t*)&Ws[b * 4608 + (wc * 32 + 16 + ln) * 72 + kk * 32 + hi8];
        acc[0][0] = __builtin_amdgcn_mfma_f32_16x16x32_bf16(a0, b0, acc[0][0], 0, 0, 0);
        acc[0][1] = __builtin_amdgcn_mfma_f32_16x16x32_bf16(a0, b1, acc[0][1], 0, 0, 0);
        acc[1][0] = __builtin_amdgcn_mfma_f32_16x16x32_bf16(a1, b0, acc[1][0], 0, 0, 0);
        acc[1][1] = __builtin_amdgcn_mfma_f32_16x16x32_bf16(a1, b1, acc[1][1], 0, 0, 0);
      }
      if (t < 3) commitT(b ^ 1);
      __syncthreads();
    }

    #pragma unroll
    for (int mi = 0; mi < 2; ++mi)
      #pragma unroll
      for (int ni = 0; ni < 2; ++ni) {
        const int col = col0 + wc * 32 + ni * 16 + ln;
        const float bval = bg1[col];
        #pragma unroll
        for (int r = 0; r < 4; ++r) {
          const int row = row0 + wr * 32 + mi * 16 + hi4 + r;
          float vx = acc[mi][ni][r] + bval;
          vx = vx * sigmoid_f(vx);
          t1b[(size_t)row * 256 + col] = f2bf(vx);
        }
      }
    return;
  }

  // ---- prep path ----
  const int pb = blk - 512;
  const int ch = pb & 15, h = pb >> 4;
  const int t0 = ch * CCH;
  ushort* K_lds = (ushort*)smem;                  // 32*KSTR
  ushort* Q_lds = (ushort*)(smem + 16896);        // 32*KSTR
  float*  G_lds = (float*)(smem + 33792);         // 32*32
  float*  ea    = (float*)(smem + 37888);         // 64 floats
  float*  scal  = (float*)(smem + 38144);         // 100

  const ushort* kg = kb + (size_t)(h * S_ + t0) * F_;
  const ushort* qg = qb + (size_t)(h * S_ + t0) * F_;
  #pragma unroll
  for (int w = 0; w < 4; ++w) {
    int o = w * 256 + tid; int t = o >> 5, c8 = (o & 31) << 3;
    *(short8_t*)&K_lds[t * KSTR + c8] = *(const short8_t*)&kg[(size_t)t * F_ + c8];
    *(short8_t*)&Q_lds[t * KSTR + c8] = *(const short8_t*)&qg[(size_t)t * F_ + c8];
  }
  if (tid < CCH)            ea[tid] = eta[(size_t)h * S_ + t0 + tid];
  else if (tid < 2 * CCH)   ea[tid] = alpha[(size_t)h * S_ + t0 + tid - CCH];
  __syncthreads();

  // transposed K copy: Ktg[h][c][t]
  {
    const int tt = tid & 31, cl = tid >> 5;
    for (int cp = 0; cp < 32; ++cp) {
      const int c = cp * 8 + cl;
      Ktg[((size_t)h * F_ + c) * S_ + t0 + tt] = K_lds[tt * KSTR + c];
    }
  }

  {
    const int tI = wv >> 1, tJ = wv & 1;
    f32x4 accG = {0.f, 0.f, 0.f, 0.f};
    f32x4 accQ = {0.f, 0.f, 0.f, 0.f};
    #pragma unroll
    for (int ko = 0; ko < 8; ++ko) {
      const int cb = ko * 32 + hi8;
      short8_t bfr = *(const short8_t*)&K_lds[(tJ * 16 + ln) * KSTR + cb];
      short8_t aK  = *(const short8_t*)&K_lds[(tI * 16 + ln) * KSTR + cb];
      short8_t aQ  = *(const short8_t*)&Q_lds[(tI * 16 + ln) * KSTR + cb];
      accG = __builtin_amdgcn_mfma_f32_16x16x32_bf16(aK, bfr, accG, 0, 0, 0);
      accQ = __builtin_amdgcn_mfma_f32_16x16x32_bf16(aQ, bfr, accQ, 0, 0, 0);
    }
    ushort* Gqo = Gqg + (size_t)(h * NCH + ch) * (CCH * CCH);
    #pragma unroll
    for (int r = 0; r < 4; ++r) {
      const int t = tI * 16 + hi4 + r, s = tJ * 16 + ln;
      G_lds[t * CCH + s] = accG[r];
      Gqo[t * CCH + s] = (s < t) ? f2bf(accQ[r]) : (ushort)0;
    }
  }
  if (tid == 0) {
    float gp = 1.f;
    for (int t = 0; t < CCH; ++t) {
      const float a = ea[CCH + t], e = ea[t];
      const float gm = gp * a;
      scal[t]           = e / a;    // b_t
      scal[CCH + t]     = e / gm;   // c_t
      scal[2 * CCH + t] = gp;       // gamma_prev
      gp = gm;
    }
    scal[3 * CCH] = gp;             // gamma_C
  }
  __syncthreads();

  // forward substitution: column j of T
  {
    const int j = tid >> 3, g = tid & 7;
    float x0 = 0.f, x1 = 0.f, x2 = 0.f, x3 = 0.f;
    ushort* To = Tg + (size_t)(h * NCH + ch) * (CCH * CCH);
    #pragma unroll
    for (int t = 0; t < CCH; ++t) {
      float p = 0.f;
      const f32x4 gr = *(const f32x4*)&G_lds[t * CCH + 4 * g];
      if (4 * g + 0 < t) p += gr[0] * x0;
      if (4 * g + 1 < t) p += gr[1] * x1;
      if (4 * g + 2 < t) p += gr[2] * x2;
      if (4 * g + 3 < t) p += gr[3] * x3;
      const float tot = red8(p);
      const float xt = ((t == j) ? 1.f : 0.f) - scal[t] * tot;
      if (g == (t >> 2)) {
        if ((t & 3) == 0) x0 = xt; else if ((t & 3) == 1) x1 = xt;
        else if ((t & 3) == 2) x2 = xt; else x3 = xt;
      }
      if (g == 0) To[t * CCH + j] = f2bf(xt);
    }
  }
  if (tid < 97) Sg[(size_t)(h * NCH + ch) * 128 + tid] = scal[tid];
}

// ---------- fused output GEMM + bias + residual + LayerNorm ----------
__global__ __launch_bounds__(256) void gemmo_ln_k(
    const ushort* __restrict__ A, const ushort* __restrict__ Wt,
    const float* __restrict__ bo, const float* __restrict__ x,
    const float* __restrict__ gamma, const float* __restrict__ beta,
    float* __restrict__ y)
{
  __shared__ ushort As[2][32 * 72];
  __shared__ ushort Ws[2][256 * 72];
  __shared__ float rs_[2][32];
  __shared__ float rq_[2][32];
  const int tid = threadIdx.x;
  const int wv = tid >> 6, l = tid & 63;
  const int ln = l & 15, hi = l >> 4, hi4 = hi << 2, hi8 = hi << 3;
  const int g = wv >> 1, chf = wv & 1;
  const int row0 = blockIdx.x * 32;

  short8_t pA, pW[8];
  auto loadT = [&](int k0) {
    { const int r = tid >> 3, c8 = (tid & 7) << 3;
      pA = *(const short8_t*)&A[(size_t)(row0 + r) * 256 + k0 + c8]; }
    #pragma unroll
    for (int p = 0; p < 8; ++p) {
      const int idx = (p << 8) + tid;
      const int n = idx >> 3, c8 = (idx & 7) << 3;
      pW[p] = *(const short8_t*)&Wt[(size_t)n * 256 + k0 + c8];
    }
  };
  auto commitT = [&](int b) {
    { const int r = tid >> 3, c8 = (tid & 7) << 3;
      *(short8_t*)&As[b][r * 72 + c8] = pA; }
    #pragma unroll
    for (int p = 0; p < 8; ++p) {
      const int idx = (p << 8) + tid;
      const int n = idx >> 3, c8 = (idx & 7) << 3;
      *(short8_t*)&Ws[b][n * 72 + c8] = pW[p];
    }
  };

  f32x4 acc[8];
  #pragma unroll
  for (int nt = 0; nt < 8; ++nt)
    #pragma unroll
    for (int r = 0; r < 4; ++r) acc[nt][r] = 0.f;

  loadT(0); commitT(0); __syncthreads();
  #pragma unroll
  for (int t = 0; t < 4; ++t) {
    const int b = t & 1;
    if (t < 3) loadT((t + 1) << 6);
    #pragma unroll
    for (int kk = 0; kk < 2; ++kk) {
      short8_t a = *(const short8_t*)&As[b][(g * 16 + ln) * 72 + kk * 32 + hi8];
      #pragma unroll
      for (int nt = 0; nt < 8; ++nt) {
        short8_t bb = *(const short8_t*)&Ws[b][(chf * 128 + nt * 16 + ln) * 72 + kk * 32 + hi8];
        acc[nt] = __builtin_amdgcn_mfma_f32_16x16x32_bf16(a, bb, acc[nt], 0, 0, 0);
      }
    }
    if (t < 3) commitT(b ^ 1);
    __syncthreads();
  }

  float val[8][4];
  float sm[4] = {0.f, 0.f, 0.f, 0.f}, sq[4] = {0.f, 0.f, 0.f, 0.f};
  #pragma unroll
  for (int nt = 0; nt < 8; ++nt) {
    const int col = chf * 128 + nt * 16 + ln;
    const float bv = bo[col];
    #pragma unroll
    for (int r = 0; r < 4; ++r) {
      const int row = row0 + g * 16 + hi4 + r;
      const float v = acc[nt][r] + bv + x[(size_t)row * 256 + col];
      val[nt][r] = v;
      sm[r] += v;
      sq[r] += v * v;
    }
  }
  #pragma unroll
  for (int m = 1; m < 16; m <<= 1) {
    #pragma unroll
    for (int r = 0; r < 4; ++r) {
      sm[r] += __shfl_xor(sm[r], m, 64);
      sq[r] += __shfl_xor(sq[r], m, 64);
    }
  }
  if (ln == 0) {
    #pragma unroll
    for (int r = 0; r < 4; ++r) {
      rs_[chf][g * 16 + hi4 + r] = sm[r];
      rq_[chf][g * 16 + hi4 + r] = sq[r];
    }
  }
  __syncthreads();
  #pragma unroll
  for (int r = 0; r < 4; ++r) {
    const int lr = g * 16 + hi4 + r;
    const float tot = rs_[0][lr] + rs_[1][lr];
    const float tq  = rq_[0][lr] + rq_[1][lr];
    const float mu  = tot * (1.0f / 256.0f);
    const float var = tq * (1.0f / 256.0f) - mu * mu;
    const float rstd = rsqrtf(var + 1e-5f);
    #pragma unroll
    for (int nt = 0; nt < 8; ++nt) {
      const int col = chf * 128 + nt * 16 + ln;
      y[(size_t)(row0 + lr) * 256 + col] =
          (val[nt][r] - mu) * rstd * gamma[col] + beta[col];
    }
  }
}

// ---------- fused knorm + etaalpha ----------
__global__ __launch_bounds__(256) void knea_k(
    const float* __restrict__ kf, ushort* __restrict__ kb,
    const float* __restrict__ sesa,
    const float* __restrict__ We2, const float* __restrict__ be2,
    const float* __restrict__ Wa2, const float* __restrict__ ba2,
    float* __restrict__ eta, float* __restrict__ alpha)
{
  const int lane = threadIdx.x & 63;
  const size_t row = ((size_t)blockIdx.x << 2) + (threadIdx.x >> 6);
  {
    const size_t off = row * F_ + ((size_t)lane << 2);
    float4 v = *(const float4*)&kf[off];
    float ss = v.x * v.x + v.y * v.y + v.z * v.z + v.w * v.w;
    #pragma unroll
    for (int m = 1; m < 64; m <<= 1) ss += __shfl_xor(ss, m, 64);
    const float sc = 1.0f / fmaxf(sqrtf(ss), 1e-12f);
    ushort4 o;
    o.x = f2bf(v.x * sc); o.y = f2bf(v.y * sc);
    o.z = f2bf(v.z * sc); o.w = f2bf(v.w * sc);
    *(ushort4*)&kb[off] = o;
  }
  {
    float pe = sesa[row * 128 + lane] * We2[lane];
    float pa = sesa[row * 128 + 64 + lane] * Wa2[lane];
    #pragma unroll
    for (int m = 1; m < 64; m <<= 1) {
      pe += __shfl_xor(pe, m, 64);
      pa += __shfl_xor(pa, m, 64);
    }
    if (lane == 0) {
      eta[row]   = sigmoid_f(pe + be2[0]) * 0.1f + 0.01f;
      alpha[row] = sigmoid_f(pa + ba2[0]) * 0.5f + 0.5f;
    }
  }
}

// ---- chunked scan v7: TWO slices per block (same head) — all operand frags
// (K/Q/Kt/T/Gq/scal) shared between chains; per-chain only V/M/R/Wt/QM/out.
// Independent dual chains fill each other's MFMA/LDS latency. Grid 128.
__global__ __launch_bounds__(256, 1) void scan_chunk_k(
    const ushort* __restrict__ kb, const ushort* __restrict__ qb,
    const ushort* __restrict__ vhb, const ushort* __restrict__ Ktg,
    const ushort* __restrict__ Tg, const ushort* __restrict__ Gqg,
    const float* __restrict__ Sg,
    ushort* __restrict__ outb, float* __restrict__ Mout)
{
  __shared__ ushort M_lds[2][16 * KSTR];    // 16.9KB
  __shared__ ushort Wt_lds[2][16 * TSTR];
  __shared__ ushort R_lds[2][16 * TSTR];
  __shared__ float  QM_lds[2][CCH * 20];

  const int tid = threadIdx.x;
  const int flat = blockIdx.x;                     // 0..127
  const int h = (flat & 7) + ((flat >> 6) << 3);   // XCD-aware remap
  const int sp = (flat >> 3) & 7;                  // slice pair
  const int r0 = sp * 32;                          // chain cn covers r0+cn*16
  const int wv = tid >> 6, l = tid & 63;
  const int ln = l & 15, hi = l >> 4, hi4 = hi << 2, hi8 = hi << 3;

  {
    ushort* mb = &M_lds[0][0];
    for (int u = tid; u < 2 * 16 * KSTR / 8; u += 256) {
      short8_t z = {0, 0, 0, 0, 0, 0, 0, 0};
      *(short8_t*)&mb[u * 8] = z;
    }
  }
  f32x4 Mf[2][4];
  #pragma unroll
  for (int cn = 0; cn < 2; ++cn)
    #pragma unroll
    for (int q = 0; q < 4; ++q)
      #pragma unroll
      for (int r = 0; r < 4; ++r) Mf[cn][q][r] = 0.f;

  const ushort* kgh = kb + (size_t)h * S_ * F_;
  const ushort* qgh = qb + (size_t)h * S_ * F_;
  const ushort* kth = Ktg + (size_t)h * F_ * S_;
  const ushort* vgh = vhb + (size_t)h * S_ * F_;

  struct Frags {
    short8_t P[8];          // K frags (wv<2) or Q frags (wv>=2)
    short8_t Kt[4];
    short8_t T, Gq;         // wv<2 only
    ushort   V[2][4];       // per-chain V, wv<2 only
    float    b[4], c[4], gp[4];  // wv<2 only
    float    gC;
  };
  Frags fA, fB;

  auto loadchunk = [&](int ch, Frags& f) {
    const int t0 = ch * CCH;
    if (wv < 2) {
      #pragma unroll
      for (int ko = 0; ko < 8; ++ko)
        f.P[ko] = *(const short8_t*)&kgh[(size_t)(t0 + wv * 16 + ln) * F_ + ko * 32 + hi8];
      const size_t tb = (size_t)(h * NCH + ch) * (CCH * CCH);
      f.T  = *(const short8_t*)&Tg [tb + (size_t)(wv * 16 + ln) * CCH + hi8];
      f.Gq = *(const short8_t*)&Gqg[tb + (size_t)(wv * 16 + ln) * CCH + hi8];
      const size_t sb = (size_t)(h * NCH + ch) * 128;
      #pragma unroll
      for (int r = 0; r < 4; ++r) {
        const int t = wv * 16 + hi4 + r;
        f.V[0][r] = vgh[(size_t)(t0 + t) * F_ + r0 + ln];
        f.V[1][r] = vgh[(size_t)(t0 + t) * F_ + r0 + 16 + ln];
        f.b[r]  = Sg[sb + t];
        f.c[r]  = Sg[sb + 32 + t];
        f.gp[r] = Sg[sb + 64 + t];
      }
    } else {
      #pragma unroll
      for (int ko = 0; ko < 8; ++ko)
        f.P[ko] = *(const short8_t*)&qgh[(size_t)(t0 + (wv - 2) * 16 + ln) * F_ + ko * 32 + hi8];
    }
    #pragma unroll
    for (int qq = 0; qq < 4; ++qq)
      f.Kt[qq] = *(const short8_t*)&kth[(size_t)((wv * 4 + qq) * 16 + ln) * S_ + t0 + hi8];
    f.gC = Sg[(size_t)(h * NCH + ch) * 128 + 96];
  };

  auto CHUNK = [&](int ch, const Frags& f) {
    const int t0 = ch * CCH;
    // ---- P2: wv<2: KM -> RHS -> R (both chains) ; wv>=2: QM (both chains) ----
    if (wv < 2) {
      #pragma unroll
      for (int cn = 0; cn < 2; ++cn) {
        f32x4 a0 = {0.f, 0.f, 0.f, 0.f}, a1 = {0.f, 0.f, 0.f, 0.f};
        #pragma unroll
        for (int ko = 0; ko < 4; ++ko) {
          short8_t b0 = *(const short8_t*)&M_lds[cn][ln * KSTR + (2 * ko) * 32 + hi8];
          a0 = __builtin_amdgcn_mfma_f32_16x16x32_bf16(f.P[2 * ko], b0, a0, 0, 0, 0);
          short8_t b1 = *(const short8_t*)&M_lds[cn][ln * KSTR + (2 * ko + 1) * 32 + hi8];
          a1 = __builtin_amdgcn_mfma_f32_16x16x32_bf16(f.P[2 * ko + 1], b1, a1, 0, 0, 0);
        }
        ushort4 rw;
        float rv[4];
        #pragma unroll
        for (int r = 0; r < 4; ++r) {
          const float s = a0[r] + a1[r];
          rv[r] = f.c[r] * bf2f(f.V[cn][r]) - f.b[r] * s;
        }
        rw.x = f2bf(rv[0]); rw.y = f2bf(rv[1]); rw.z = f2bf(rv[2]); rw.w = f2bf(rv[3]);
        *(ushort4*)&R_lds[cn][ln * TSTR + wv * 16 + hi4] = rw;
      }
    } else {
      #pragma unroll
      for (int cn = 0; cn < 2; ++cn) {
        f32x4 a0 = {0.f, 0.f, 0.f, 0.f}, a1 = {0.f, 0.f, 0.f, 0.f};
        #pragma unroll
        for (int ko = 0; ko < 4; ++ko) {
          short8_t b0 = *(const short8_t*)&M_lds[cn][ln * KSTR + (2 * ko) * 32 + hi8];
          a0 = __builtin_amdgcn_mfma_f32_16x16x32_bf16(f.P[2 * ko], b0, a0, 0, 0, 0);
          short8_t b1 = *(const short8_t*)&M_lds[cn][ln * KSTR + (2 * ko + 1) * 32 + hi8];
          a1 = __builtin_amdgcn_mfma_f32_16x16x32_bf16(f.P[2 * ko + 1], b1, a1, 0, 0, 0);
        }
        #pragma unroll
        for (int r = 0; r < 4; ++r)
          QM_lds[cn][((wv - 2) * 16 + hi4 + r) * 20 + ln] = a0[r] + a1[r];
      }
    }
    BARX();

    // ---- P3: W = T @ R (waves 0,1; both chains) ----
    if (wv < 2) {
      #pragma unroll
      for (int cn = 0; cn < 2; ++cn) {
        short8_t bfr = *(const short8_t*)&R_lds[cn][ln * TSTR + hi8];
        f32x4 z = {0.f, 0.f, 0.f, 0.f};
        f32x4 d = __builtin_amdgcn_mfma_f32_16x16x32_bf16(f.T, bfr, z, 0, 0, 0);
        ushort4 wo;
        wo.x = f2bf(d[0]); wo.y = f2bf(d[1]); wo.z = f2bf(d[2]); wo.w = f2bf(d[3]);
        *(ushort4*)&Wt_lds[cn][ln * TSTR + wv * 16 + hi4] = wo;
      }
    }
    BARX();

    // ---- P4: M update (all waves; both chains) + OUT (waves 0,1) ----
    #pragma unroll
    for (int cn = 0; cn < 2; ++cn) {
      short8_t aw = *(const short8_t*)&Wt_lds[cn][ln * TSTR + hi8];
      #pragma unroll
      for (int qq = 0; qq < 4; ++qq) {
        const int jt = wv * 4 + qq;
        f32x4 d = __builtin_amdgcn_mfma_f32_16x16x32_bf16(aw, f.Kt[qq], Mf[cn][qq], 0, 0, 0);
        #pragma unroll
        for (int r = 0; r < 4; ++r) {
          const float nv = f.gC * d[r];
          Mf[cn][qq][r] = nv;
          M_lds[cn][(hi4 + r) * KSTR + jt * 16 + ln] = f2bf(nv);
        }
      }
      if (wv < 2) {
        f32x4 z = {0.f, 0.f, 0.f, 0.f};
        f32x4 d = __builtin_amdgcn_mfma_f32_16x16x32_bf16(f.Gq, aw, z, 0, 0, 0);
        #pragma unroll
        for (int r = 0; r < 4; ++r) {
          const int t = wv * 16 + hi4 + r;
          outb[(size_t)(h * S_ + t0 + t) * F_ + r0 + cn * 16 + ln] =
              f2bf(f.gp[r] * (QM_lds[cn][t * 20 + ln] + d[r]));
        }
      }
    }
    BARX();
  };

  loadchunk(0, fA);
  BARX();   // M zeros visible

  for (int ch = 0; ch < NCH; ch += 2) {
    loadchunk(ch + 1, fB);           // in flight across CHUNK(ch)
    CHUNK(ch, fA);
    if (ch + 2 < NCH) loadchunk(ch + 2, fA);
    CHUNK(ch + 1, fB);
  }

  #pragma unroll
  for (int cn = 0; cn < 2; ++cn)
    #pragma unroll
    for (int qq = 0; qq < 4; ++qq) {
      const int jt = wv * 4 + qq;
      #pragma unroll
      for (int r = 0; r < 4; ++r)
        Mout[((size_t)h * F_ + r0 + cn * 16 + hi4 + r) * F_ + jt * 16 + ln] = Mf[cn][qq][r];
    }
}

extern "C" void kernel_launch(void* const* d_in, const int* in_sizes, int n_in,
                              void* d_out, int out_size, void* d_ws, size_t ws_size,
                              hipStream_t stream)
{
  const float* x    = (const float*)d_in[0];
  const float* Wq   = (const float*)d_in[1];
  const float* Wk   = (const float*)d_in[2];
  const float* Wv   = (const float*)d_in[3];
  const float* Wg1  = (const float*)d_in[4];
  const float* bg1  = (const float*)d_in[5];
  const float* Wg2  = (const float*)d_in[6];
  const float* bg2  = (const float*)d_in[7];
  const float* We1  = (const float*)d_in[8];
  const float* be1  = (const float*)d_in[9];
  const float* We2  = (const float*)d_in[10];
  const float* be2  = (const float*)d_in[11];
  const float* Wa1  = (const float*)d_in[12];
  const float* ba1  = (const float*)d_in[13];
  const float* Wa2  = (const float*)d_in[14];
  const float* ba2  = (const float*)d_in[15];
  const float* Wo   = (const float*)d_in[16];
  const float* bo   = (const float*)d_in[17];
  const float* gamma= (const float*)d_in[18];
  const float* beta = (const float*)d_in[19];

  const int Mrows = NH_ * S_;               // 8192
  const size_t MM = 1048576;                // 1M floats
  const size_t NTF = 2 * MM;

  float* ws = (float*)d_ws;
  ushort* outb = (ushort*)(ws + 0 * MM);   // scan output (bf16)
  ushort* qb   = (ushort*)(ws + 1 * MM);
  ushort* kb   = (ushort*)(ws + 2 * MM);
  float*  kf   = ws + 3 * MM;              // f32 [3M,5M); dead after knea
  ushort* t1b  = (ushort*)(ws + 3 * MM);   // reuse after knea
  ushort* vhb  = (ushort*)(ws + 4 * MM);   // bf16 v_hat
  ushort* vb   = (ushort*)(ws + 5 * MM);   // bf16 v; dead after g1 gemm
  float*  sesa = ws + 6 * MM;              // f32 [6M,7M); dead after knea
  float*  eta  = ws + 7 * MM;
  float*  alpha= eta + Mrows;
  ushort* Tg   = (ushort*)(ws + 7 * MM + 16384);
  ushort* Gqg  = Tg + 262144;
  float*  Sg   = ws + 7 * MM + 16384 + 131072 + 131072;
  ushort* Ktg  = (ushort*)(Sg + 32768);
  ushort* Wt   = Ktg + 2097152;
  float*  beas = (float*)(Wt + 425984);

  dim3 blk(256);

  wconv_k<<<105, blk, 0, stream>>>(Wq, Wk, Wv, Wg1, Wg2, Wo, We1, Wa1,
                                   be1, ba1, Wt, beas);

  qkve_k<<<dim3(14, 128), blk, 0, stream>>>(x, Wt, beas, qb, kf, vb, sesa);

  knea_k<<<Mrows / 4, blk, 0, stream>>>(kf, kb, sesa, We2, be2, Wa2, ba2, eta, alpha);

  // fused: g1 GEMM (blocks 0..511) + prep (blocks 512..767)
  g1prep_k<<<768, blk, 0, stream>>>(vb, Wt + 229376, bg1, t1b,
                                    kb, qb, eta, alpha, Tg, Gqg, Sg, Ktg);

  gemm_bf16_k<<<dim3(4, 128), blk, 0, stream>>>(t1b, Wt + 294912, bg2, nullptr, vhb, 0);

  float* yout = (float*)d_out;
  float* Mfin = yout + NTF;
  scan_chunk_k<<<128, blk, 0, stream>>>(kb, qb, vhb, Ktg, Tg, Gqg, Sg, outb, Mfin);

  gemmo_ln_k<<<256, blk, 0, stream>>>(outb, Wt + 360448, bo, x, gamma, beta, yout);
}

// Round 14
// 95.144 us; speedup vs baseline: 1.1700x; 1.1700x over previous
//
#include <hip/hip_runtime.h>

#define F_ 256
#define S_ 512
#define NH_ 16
#define CCH 32
#define NCH (S_/CCH)
#define KSTR 264   // bf16 row stride for [32][256] LDS tiles
#define KTSTR 36   // bf16 row stride for Kt [256][32] tile
#define TSTR 40    // bf16 row stride for 32x32-ish tiles

typedef __attribute__((ext_vector_type(8))) short short8_t;
typedef __attribute__((ext_vector_type(4))) float f32x4;

__device__ __forceinline__ float sigmoid_f(float x) { return 1.0f / (1.0f + __expf(-x)); }

__device__ __forceinline__ ushort f2bf(float x) {   // RNE float->bf16
  uint u = __float_as_uint(x);
  u += 0x7FFFu + ((u >> 16) & 1u);
  return (ushort)(u >> 16);
}
__device__ __forceinline__ float bf2f(ushort u) {
  return __uint_as_float((uint)u << 16);
}

template<int CTRL>
__device__ __forceinline__ float dpp_add(float x) {
  int y = __builtin_amdgcn_update_dpp(0, __float_as_int(x), CTRL, 0xf, 0xf, true);
  return x + __int_as_float(y);
}
// butterfly sum over aligned 8-lane groups, result in all 8 lanes
__device__ __forceinline__ float red8(float x) {
  x = dpp_add<0xB1>(x);
  x = dpp_add<0x4E>(x);
  x = dpp_add<0x141>(x);
  return x;
}

// ---------- one-time: weight transpose->bf16 + bias concat ----------
// Wt row layout (ushort offsets): q=0 k=65536 v=131072 e1=196608 a1=212992
//                                 g1=229376 g2=294912 o=360448
__global__ __launch_bounds__(256) void wconv_k(
    const float* __restrict__ Wq, const float* __restrict__ Wk,
    const float* __restrict__ Wv, const float* __restrict__ Wg1,
    const float* __restrict__ Wg2, const float* __restrict__ Wo,
    const float* __restrict__ We1, const float* __restrict__ Wa1,
    const float* __restrict__ be1, const float* __restrict__ ba1,
    ushort* __restrict__ Wt, float* __restrict__ beas)
{
  const int blk = blockIdx.x, tid = threadIdx.x;
  if (blk == 104) {
    if (tid < 64) beas[tid] = be1[tid];
    else if (tid < 128) beas[tid] = ba1[tid - 64];
    return;
  }
  __shared__ float tile[64][65];
  const float* src; int N, k0, n0; size_t dstbase;
  if (blk < 96) {
    const int w = blk >> 4, tl = blk & 15;
    const float* ws_[6] = {Wq, Wk, Wv, Wg1, Wg2, Wo};
    const size_t dstb[6] = {0, 65536, 131072, 229376, 294912, 360448};
    src = ws_[w]; N = 256;
    k0 = (tl >> 2) * 64; n0 = (tl & 3) * 64;
    dstbase = dstb[w];
  } else {
    const int w = (blk - 96) >> 2, tl = (blk - 96) & 3;
    src = w ? Wa1 : We1; N = 64;
    k0 = tl * 64; n0 = 0;
    dstbase = w ? 212992 : 196608;
  }
  #pragma unroll
  for (int p = 0; p < 4; ++p) {
    const int idx = (p << 8) + tid;
    const int r = idx >> 4, c4 = (idx & 15) << 2;
    if (c4 < N) {
      const float4 v = *(const float4*)&src[(size_t)(k0 + r) * N + n0 + c4];
      tile[r][c4 + 0] = v.x; tile[r][c4 + 1] = v.y;
      tile[r][c4 + 2] = v.z; tile[r][c4 + 3] = v.w;
    }
  }
  __syncthreads();
  #pragma unroll
  for (int p = 0; p < 4; ++p) {
    const int idx = (p << 8) + tid;
    const int nl = idx >> 4, kc = (idx & 15) << 2;
    if ((n0 + nl) < ((blk < 96) ? 256 : 64)) {
      ushort4 o;
      o.x = f2bf(tile[kc + 0][nl]); o.y = f2bf(tile[kc + 1][nl]);
      o.z = f2bf(tile[kc + 2][nl]); o.w = f2bf(tile[kc + 3][nl]);
      *(ushort4*)&Wt[dstbase + (size_t)(n0 + nl) * 256 + k0 + kc] = o;
    }
  }
}

// ---------- fused QKVE GEMM: out = f2bf(x) @ [Wq|Wk|Wv|We1|Wa1] ----------
__global__ __launch_bounds__(256) void qkve_k(
    const float* __restrict__ x, const ushort* __restrict__ Wt,
    const float* __restrict__ beas,
    ushort* __restrict__ qb, float* __restrict__ kf,
    ushort* __restrict__ vb, float* __restrict__ sesa)
{
  __shared__ ushort As[2][64 * 72];
  __shared__ ushort Ws[2][64 * 72];
  const int tid = threadIdx.x;
  const int wv = tid >> 6, l = tid & 63;
  const int ln = l & 15, hi = l >> 4, hi4 = hi << 2, hi8 = hi << 3;
  const int wr = wv >> 1, wc = wv & 1;
  const int row0 = blockIdx.y * 64, col0 = blockIdx.x * 64;
  const int r_ = tid >> 3, c8_ = (tid & 7) << 3;

  float4 pAf[4];
  short8_t pB[2];
  auto loadT = [&](int k0) {
    pAf[0] = *(const float4*)&x[(size_t)(row0 + r_) * 256 + k0 + c8_];
    pAf[1] = *(const float4*)&x[(size_t)(row0 + r_) * 256 + k0 + c8_ + 4];
    pAf[2] = *(const float4*)&x[(size_t)(row0 + 32 + r_) * 256 + k0 + c8_];
    pAf[3] = *(const float4*)&x[(size_t)(row0 + 32 + r_) * 256 + k0 + c8_ + 4];
    pB[0] = *(const short8_t*)&Wt[(size_t)(col0 + r_) * 256 + k0 + c8_];
    pB[1] = *(const short8_t*)&Wt[(size_t)(col0 + 32 + r_) * 256 + k0 + c8_];
  };
  auto commitT = [&](int b) {
    #pragma unroll
    for (int h = 0; h < 2; ++h) {
      short8_t s;
      s[0] = (short)f2bf(pAf[h*2].x); s[1] = (short)f2bf(pAf[h*2].y);
      s[2] = (short)f2bf(pAf[h*2].z); s[3] = (short)f2bf(pAf[h*2].w);
      s[4] = (short)f2bf(pAf[h*2+1].x); s[5] = (short)f2bf(pAf[h*2+1].y);
      s[6] = (short)f2bf(pAf[h*2+1].z); s[7] = (short)f2bf(pAf[h*2+1].w);
      *(short8_t*)&As[b][(h * 32 + r_) * 72 + c8_] = s;
    }
    *(short8_t*)&Ws[b][r_ * 72 + c8_] = pB[0];
    *(short8_t*)&Ws[b][(32 + r_) * 72 + c8_] = pB[1];
  };

  f32x4 acc[2][2];
  #pragma unroll
  for (int i = 0; i < 2; ++i)
    #pragma unroll
    for (int j = 0; j < 2; ++j)
      #pragma unroll
      for (int r = 0; r < 4; ++r) acc[i][j][r] = 0.f;

  loadT(0); commitT(0); __syncthreads();
  #pragma unroll
  for (int t = 0; t < 4; ++t) {
    const int b = t & 1;
    if (t < 3) loadT((t + 1) << 6);
    #pragma unroll
    for (int kk = 0; kk < 2; ++kk) {
      short8_t a0 = *(const short8_t*)&As[b][(wr * 32 + ln) * 72 + kk * 32 + hi8];
      short8_t a1 = *(const short8_t*)&As[b][(wr * 32 + 16 + ln) * 72 + kk * 32 + hi8];
      short8_t b0 = *(const short8_t*)&Ws[b][(wc * 32 + ln) * 72 + kk * 32 + hi8];
      short8_t b1 = *(const short8_t*)&Ws[b][(wc * 32 + 16 + ln) * 72 + kk * 32 + hi8];
      acc[0][0] = __builtin_amdgcn_mfma_f32_16x16x32_bf16(a0, b0, acc[0][0], 0, 0, 0);
      acc[0][1] = __builtin_amdgcn_mfma_f32_16x16x32_bf16(a0, b1, acc[0][1], 0, 0, 0);
      acc[1][0] = __builtin_amdgcn_mfma_f32_16x16x32_bf16(a1, b0, acc[1][0], 0, 0, 0);
      acc[1][1] = __builtin_amdgcn_mfma_f32_16x16x32_bf16(a1, b1, acc[1][1], 0, 0, 0);
    }
    if (t < 3) commitT(b ^ 1);
    __syncthreads();
  }

  #pragma unroll
  for (int mi = 0; mi < 2; ++mi)
    #pragma unroll
    for (int ni = 0; ni < 2; ++ni) {
      const int col = col0 + wc * 32 + ni * 16 + ln;
      #pragma unroll
      for (int r = 0; r < 4; ++r) {
        const int row = row0 + wr * 32 + mi * 16 + hi4 + r;
        float vx = acc[mi][ni][r];
        if (col0 < 256)      qb[(size_t)row * 256 + col] = f2bf(vx);
        else if (col0 < 512) kf[(size_t)row * 256 + (col - 256)] = vx;
        else if (col0 < 768) vb[(size_t)row * 256 + (col - 512)] = f2bf(vx);
        else {
          const int cc = col - 768;
          vx += beas[cc];
          vx *= sigmoid_f(vx);
          sesa[(size_t)row * 128 + cc] = vx;
        }
      }
    }
}

// ---------- generic bf16 GEMM (N=256,K=256): C = act(A @ W + bias) ----------
__global__ __launch_bounds__(256) void gemm_bf16_k(
    const ushort* __restrict__ A, const ushort* __restrict__ Wt,
    const float* __restrict__ bias, float* __restrict__ Cf,
    ushort* __restrict__ Cb, int act)
{
  __shared__ ushort As[2][64 * 72];
  __shared__ ushort Ws[2][64 * 72];
  const int tid = threadIdx.x;
  const int wv = tid >> 6, l = tid & 63;
  const int ln = l & 15, hi = l >> 4, hi4 = hi << 2, hi8 = hi << 3;
  const int wr = wv >> 1, wc = wv & 1;
  const int row0 = blockIdx.y * 64, col0 = blockIdx.x * 64;
  const int r_ = tid >> 3, c8_ = (tid & 7) << 3;

  short8_t pA[2], pB[2];
  auto loadT = [&](int k0) {
    pA[0] = *(const short8_t*)&A[(size_t)(row0 + r_) * 256 + k0 + c8_];
    pA[1] = *(const short8_t*)&A[(size_t)(row0 + 32 + r_) * 256 + k0 + c8_];
    pB[0] = *(const short8_t*)&Wt[(size_t)(col0 + r_) * 256 + k0 + c8_];
    pB[1] = *(const short8_t*)&Wt[(size_t)(col0 + 32 + r_) * 256 + k0 + c8_];
  };
  auto commitT = [&](int b) {
    *(short8_t*)&As[b][r_ * 72 + c8_] = pA[0];
    *(short8_t*)&As[b][(32 + r_) * 72 + c8_] = pA[1];
    *(short8_t*)&Ws[b][r_ * 72 + c8_] = pB[0];
    *(short8_t*)&Ws[b][(32 + r_) * 72 + c8_] = pB[1];
  };

  f32x4 acc[2][2];
  #pragma unroll
  for (int i = 0; i < 2; ++i)
    #pragma unroll
    for (int j = 0; j < 2; ++j)
      #pragma unroll
      for (int r = 0; r < 4; ++r) acc[i][j][r] = 0.f;

  loadT(0); commitT(0); __syncthreads();
  #pragma unroll
  for (int t = 0; t < 4; ++t) {
    const int b = t & 1;
    if (t < 3) loadT((t + 1) << 6);
    #pragma unroll
    for (int kk = 0; kk < 2; ++kk) {
      short8_t a0 = *(const short8_t*)&As[b][(wr * 32 + ln) * 72 + kk * 32 + hi8];
      short8_t a1 = *(const short8_t*)&As[b][(wr * 32 + 16 + ln) * 72 + kk * 32 + hi8];
      short8_t b0 = *(const short8_t*)&Ws[b][(wc * 32 + ln) * 72 + kk * 32 + hi8];
      short8_t b1 = *(const short8_t*)&Ws[b][(wc * 32 + 16 + ln) * 72 + kk * 32 + hi8];
      acc[0][0] = __builtin_amdgcn_mfma_f32_16x16x32_bf16(a0, b0, acc[0][0], 0, 0, 0);
      acc[0][1] = __builtin_amdgcn_mfma_f32_16x16x32_bf16(a0, b1, acc[0][1], 0, 0, 0);
      acc[1][0] = __builtin_amdgcn_mfma_f32_16x16x32_bf16(a1, b0, acc[1][0], 0, 0, 0);
      acc[1][1] = __builtin_amdgcn_mfma_f32_16x16x32_bf16(a1, b1, acc[1][1], 0, 0, 0);
    }
    if (t < 3) commitT(b ^ 1);
    __syncthreads();
  }

  #pragma unroll
  for (int mi = 0; mi < 2; ++mi)
    #pragma unroll
    for (int ni = 0; ni < 2; ++ni) {
      const int col = col0 + wc * 32 + ni * 16 + ln;
      const float bval = bias ? bias[col] : 0.f;
      #pragma unroll
      for (int r = 0; r < 4; ++r) {
        const int row = row0 + wr * 32 + mi * 16 + hi4 + r;
        float vx = acc[mi][ni][r] + bval;
        if (act == 1) vx = vx * sigmoid_f(vx);
        if (Cf) Cf[(size_t)row * 256 + col] = vx;
        if (Cb) Cb[(size_t)row * 256 + col] = f2bf(vx);
      }
    }
}

// ---------- fused g1-GEMM (blocks 0..511) + prep (blocks 512..767) ----------
__global__ __launch_bounds__(256) void g1prep_k(
    const ushort* __restrict__ vb, const ushort* __restrict__ WtG1,
    const float* __restrict__ bg1, ushort* __restrict__ t1b,
    const ushort* __restrict__ kb, const ushort* __restrict__ qb,
    const float* __restrict__ eta, const float* __restrict__ alpha,
    ushort* __restrict__ Tg, ushort* __restrict__ Gqg, float* __restrict__ Sg,
    ushort* __restrict__ Ktg)
{
  __shared__ __align__(16) char smem[38592];
  const int blk = blockIdx.x;
  const int tid = threadIdx.x;
  const int l = tid & 63, wv = tid >> 6;
  const int ln = l & 15, hi = l >> 4, hi4 = hi << 2, hi8 = hi << 3;

  if (blk < 512) {
    // ---- g1 GEMM: t1b = silu(vb @ Wg1 + bg1) ----
    ushort* As = (ushort*)smem;               // [2][64*72]
    ushort* Ws = (ushort*)(smem + 18432);     // [2][64*72]
    const int wr = wv >> 1, wc = wv & 1;
    const int row0 = (blk >> 2) * 64, col0 = (blk & 3) * 64;
    const int r_ = tid >> 3, c8_ = (tid & 7) << 3;

    short8_t pA[2], pB[2];
    auto loadT = [&](int k0) {
      pA[0] = *(const short8_t*)&vb[(size_t)(row0 + r_) * 256 + k0 + c8_];
      pA[1] = *(const short8_t*)&vb[(size_t)(row0 + 32 + r_) * 256 + k0 + c8_];
      pB[0] = *(const short8_t*)&WtG1[(size_t)(col0 + r_) * 256 + k0 + c8_];
      pB[1] = *(const short8_t*)&WtG1[(size_t)(col0 + 32 + r_) * 256 + k0 + c8_];
    };
    auto commitT = [&](int b) {
      *(short8_t*)&As[b * 4608 + r_ * 72 + c8_] = pA[0];
      *(short8_t*)&As[b * 4608 + (32 + r_) * 72 + c8_] = pA[1];
      *(short8_t*)&Ws[b * 4608 + r_ * 72 + c8_] = pB[0];
      *(short8_t*)&Ws[b * 4608 + (32 + r_) * 72 + c8_] = pB[1];
    };

    f32x4 acc[2][2];
    #pragma unroll
    for (int i = 0; i < 2; ++i)
      #pragma unroll
      for (int j = 0; j < 2; ++j)
        #pragma unroll
        for (int r = 0; r < 4; ++r) acc[i][j][r] = 0.f;

    loadT(0); commitT(0); __syncthreads();
    #pragma unroll
    for (int t = 0; t < 4; ++t) {
      const int b = t & 1;
      if (t < 3) loadT((t + 1) << 6);
      #pragma unroll
      for (int kk = 0; kk < 2; ++kk) {
        short8_t a0 = *(const short8_t*)&As[b * 4608 + (wr * 32 + ln) * 72 + kk * 32 + hi8];
        short8_t a1 = *(const short8_t*)&As[b * 4608 + (wr * 32 + 16 + ln) * 72 + kk * 32 + hi8];
        short8_t b0 = *(const short8_t*)&Ws[b * 4608 + (wc * 32 + ln) * 72 + kk * 32 + hi8];
        short8_t b1 = *(const short8_t*)&Ws[b * 4608 + (wc * 32 + 16 + ln) * 72 + kk * 32 + hi8];
        acc[0][0] = __builtin_amdgcn_mfma_f32_16x16x32_bf16(a0, b0, acc[0][0], 0, 0, 0);
        acc[0][1] = __builtin_amdgcn_mfma_f32_16x16x32_bf16(a0, b1, acc[0][1], 0, 0, 0);
        acc[1][0] = __builtin_amdgcn_mfma_f32_16x16x32_bf16(a1, b0, acc[1][0], 0, 0, 0);
        acc[1][1] = __builtin_amdgcn_mfma_f32_16x16x32_bf16(a1, b1, acc[1][1], 0, 0, 0);
      }
      if (t < 3) commitT(b ^ 1);
      __syncthreads();
    }

    #pragma unroll
    for (int mi = 0; mi < 2; ++mi)
      #pragma unroll
      for (int ni = 0; ni < 2; ++ni) {
        const int col = col0 + wc * 32 + ni * 16 + ln;
        const float bval = bg1[col];
        #pragma unroll
        for (int r = 0; r < 4; ++r) {
          const int row = row0 + wr * 32 + mi * 16 + hi4 + r;
          float vx = acc[mi][ni][r] + bval;
          vx = vx * sigmoid_f(vx);
          t1b[(size_t)row * 256 + col] = f2bf(vx);
        }
      }
    return;
  }

  // ---- prep path ----
  const int pb = blk - 512;
  const int ch = pb & 15, h = pb >> 4;
  const int t0 = ch * CCH;
  ushort* K_lds = (ushort*)smem;                  // 32*KSTR
  ushort* Q_lds = (ushort*)(smem + 16896);        // 32*KSTR
  float*  G_lds = (float*)(smem + 33792);         // 32*32
  float*  ea    = (float*)(smem + 37888);         // 64 floats
  float*  scal  = (float*)(smem + 38144);         // 100

  const ushort* kg = kb + (size_t)(h * S_ + t0) * F_;
  const ushort* qg = qb + (size_t)(h * S_ + t0) * F_;
  #pragma unroll
  for (int w = 0; w < 4; ++w) {
    int o = w * 256 + tid; int t = o >> 5, c8 = (o & 31) << 3;
    *(short8_t*)&K_lds[t * KSTR + c8] = *(const short8_t*)&kg[(size_t)t * F_ + c8];
    *(short8_t*)&Q_lds[t * KSTR + c8] = *(const short8_t*)&qg[(size_t)t * F_ + c8];
  }
  if (tid < CCH)            ea[tid] = eta[(size_t)h * S_ + t0 + tid];
  else if (tid < 2 * CCH)   ea[tid] = alpha[(size_t)h * S_ + t0 + tid - CCH];
  __syncthreads();

  // transposed K copy: Ktg[h][c][t]
  {
    const int tt = tid & 31, cl = tid >> 5;
    for (int cp = 0; cp < 32; ++cp) {
      const int c = cp * 8 + cl;
      Ktg[((size_t)h * F_ + c) * S_ + t0 + tt] = K_lds[tt * KSTR + c];
    }
  }

  {
    const int tI = wv >> 1, tJ = wv & 1;
    f32x4 accG = {0.f, 0.f, 0.f, 0.f};
    f32x4 accQ = {0.f, 0.f, 0.f, 0.f};
    #pragma unroll
    for (int ko = 0; ko < 8; ++ko) {
      const int cb = ko * 32 + hi8;
      short8_t bfr = *(const short8_t*)&K_lds[(tJ * 16 + ln) * KSTR + cb];
      short8_t aK  = *(const short8_t*)&K_lds[(tI * 16 + ln) * KSTR + cb];
      short8_t aQ  = *(const short8_t*)&Q_lds[(tI * 16 + ln) * KSTR + cb];
      accG = __builtin_amdgcn_mfma_f32_16x16x32_bf16(aK, bfr, accG, 0, 0, 0);
      accQ = __builtin_amdgcn_mfma_f32_16x16x32_bf16(aQ, bfr, accQ, 0, 0, 0);
    }
    ushort* Gqo = Gqg + (size_t)(h * NCH + ch) * (CCH * CCH);
    #pragma unroll
    for (int r = 0; r < 4; ++r) {
      const int t = tI * 16 + hi4 + r, s = tJ * 16 + ln;
      G_lds[t * CCH + s] = accG[r];
      Gqo[t * CCH + s] = (s < t) ? f2bf(accQ[r]) : (ushort)0;
    }
  }
  if (tid == 0) {
    float gp = 1.f;
    for (int t = 0; t < CCH; ++t) {
      const float a = ea[CCH + t], e = ea[t];
      const float gm = gp * a;
      scal[t]           = e / a;    // b_t
      scal[CCH + t]     = e / gm;   // c_t
      scal[2 * CCH + t] = gp;       // gamma_prev
      gp = gm;
    }
    scal[3 * CCH] = gp;             // gamma_C
  }
  __syncthreads();

  // forward substitution: column j of T
  {
    const int j = tid >> 3, g = tid & 7;
    float x0 = 0.f, x1 = 0.f, x2 = 0.f, x3 = 0.f;
    ushort* To = Tg + (size_t)(h * NCH + ch) * (CCH * CCH);
    #pragma unroll
    for (int t = 0; t < CCH; ++t) {
      float p = 0.f;
      const f32x4 gr = *(const f32x4*)&G_lds[t * CCH + 4 * g];
      if (4 * g + 0 < t) p += gr[0] * x0;
      if (4 * g + 1 < t) p += gr[1] * x1;
      if (4 * g + 2 < t) p += gr[2] * x2;
      if (4 * g + 3 < t) p += gr[3] * x3;
      const float tot = red8(p);
      const float xt = ((t == j) ? 1.f : 0.f) - scal[t] * tot;
      if (g == (t >> 2)) {
        if ((t & 3) == 0) x0 = xt; else if ((t & 3) == 1) x1 = xt;
        else if ((t & 3) == 2) x2 = xt; else x3 = xt;
      }
      if (g == 0) To[t * CCH + j] = f2bf(xt);
    }
  }
  if (tid < 97) Sg[(size_t)(h * NCH + ch) * 128 + tid] = scal[tid];
}

// ---------- fused output GEMM + bias + residual + LayerNorm ----------
__global__ __launch_bounds__(256) void gemmo_ln_k(
    const ushort* __restrict__ A, const ushort* __restrict__ Wt,
    const float* __restrict__ bo, const float* __restrict__ x,
    const float* __restrict__ gamma, const float* __restrict__ beta,
    float* __restrict__ y)
{
  __shared__ ushort As[2][32 * 72];
  __shared__ ushort Ws[2][256 * 72];
  __shared__ float rs_[2][32];
  __shared__ float rq_[2][32];
  const int tid = threadIdx.x;
  const int wv = tid >> 6, l = tid & 63;
  const int ln = l & 15, hi = l >> 4, hi4 = hi << 2, hi8 = hi << 3;
  const int g = wv >> 1, chf = wv & 1;
  const int row0 = blockIdx.x * 32;

  short8_t pA, pW[8];
  auto loadT = [&](int k0) {
    { const int r = tid >> 3, c8 = (tid & 7) << 3;
      pA = *(const short8_t*)&A[(size_t)(row0 + r) * 256 + k0 + c8]; }
    #pragma unroll
    for (int p = 0; p < 8; ++p) {
      const int idx = (p << 8) + tid;
      const int n = idx >> 3, c8 = (idx & 7) << 3;
      pW[p] = *(const short8_t*)&Wt[(size_t)n * 256 + k0 + c8];
    }
  };
  auto commitT = [&](int b) {
    { const int r = tid >> 3, c8 = (tid & 7) << 3;
      *(short8_t*)&As[b][r * 72 + c8] = pA; }
    #pragma unroll
    for (int p = 0; p < 8; ++p) {
      const int idx = (p << 8) + tid;
      const int n = idx >> 3, c8 = (idx & 7) << 3;
      *(short8_t*)&Ws[b][n * 72 + c8] = pW[p];
    }
  };

  f32x4 acc[8];
  #pragma unroll
  for (int nt = 0; nt < 8; ++nt)
    #pragma unroll
    for (int r = 0; r < 4; ++r) acc[nt][r] = 0.f;

  loadT(0); commitT(0); __syncthreads();
  #pragma unroll
  for (int t = 0; t < 4; ++t) {
    const int b = t & 1;
    if (t < 3) loadT((t + 1) << 6);
    #pragma unroll
    for (int kk = 0; kk < 2; ++kk) {
      short8_t a = *(const short8_t*)&As[b][(g * 16 + ln) * 72 + kk * 32 + hi8];
      #pragma unroll
      for (int nt = 0; nt < 8; ++nt) {
        short8_t bb = *(const short8_t*)&Ws[b][(chf * 128 + nt * 16 + ln) * 72 + kk * 32 + hi8];
        acc[nt] = __builtin_amdgcn_mfma_f32_16x16x32_bf16(a, bb, acc[nt], 0, 0, 0);
      }
    }
    if (t < 3) commitT(b ^ 1);
    __syncthreads();
  }

  float val[8][4];
  float sm[4] = {0.f, 0.f, 0.f, 0.f}, sq[4] = {0.f, 0.f, 0.f, 0.f};
  #pragma unroll
  for (int nt = 0; nt < 8; ++nt) {
    const int col = chf * 128 + nt * 16 + ln;
    const float bv = bo[col];
    #pragma unroll
    for (int r = 0; r < 4; ++r) {
      const int row = row0 + g * 16 + hi4 + r;
      const float v = acc[nt][r] + bv + x[(size_t)row * 256 + col];
      val[nt][r] = v;
      sm[r] += v;
      sq[r] += v * v;
    }
  }
  #pragma unroll
  for (int m = 1; m < 16; m <<= 1) {
    #pragma unroll
    for (int r = 0; r < 4; ++r) {
      sm[r] += __shfl_xor(sm[r], m, 64);
      sq[r] += __shfl_xor(sq[r], m, 64);
    }
  }
  if (ln == 0) {
    #pragma unroll
    for (int r = 0; r < 4; ++r) {
      rs_[chf][g * 16 + hi4 + r] = sm[r];
      rq_[chf][g * 16 + hi4 + r] = sq[r];
    }
  }
  __syncthreads();
  #pragma unroll
  for (int r = 0; r < 4; ++r) {
    const int lr = g * 16 + hi4 + r;
    const float tot = rs_[0][lr] + rs_[1][lr];
    const float tq  = rq_[0][lr] + rq_[1][lr];
    const float mu  = tot * (1.0f / 256.0f);
    const float var = tq * (1.0f / 256.0f) - mu * mu;
    const float rstd = rsqrtf(var + 1e-5f);
    #pragma unroll
    for (int nt = 0; nt < 8; ++nt) {
      const int col = chf * 128 + nt * 16 + ln;
      y[(size_t)(row0 + lr) * 256 + col] =
          (val[nt][r] - mu) * rstd * gamma[col] + beta[col];
    }
  }
}

// ---------- fused knorm + etaalpha ----------
__global__ __launch_bounds__(256) void knea_k(
    const float* __restrict__ kf, ushort* __restrict__ kb,
    const float* __restrict__ sesa,
    const float* __restrict__ We2, const float* __restrict__ be2,
    const float* __restrict__ Wa2, const float* __restrict__ ba2,
    float* __restrict__ eta, float* __restrict__ alpha)
{
  const int lane = threadIdx.x & 63;
  const size_t row = ((size_t)blockIdx.x << 2) + (threadIdx.x >> 6);
  {
    const size_t off = row * F_ + ((size_t)lane << 2);
    float4 v = *(const float4*)&kf[off];
    float ss = v.x * v.x + v.y * v.y + v.z * v.z + v.w * v.w;
    #pragma unroll
    for (int m = 1; m < 64; m <<= 1) ss += __shfl_xor(ss, m, 64);
    const float sc = 1.0f / fmaxf(sqrtf(ss), 1e-12f);
    ushort4 o;
    o.x = f2bf(v.x * sc); o.y = f2bf(v.y * sc);
    o.z = f2bf(v.z * sc); o.w = f2bf(v.w * sc);
    *(ushort4*)&kb[off] = o;
  }
  {
    float pe = sesa[row * 128 + lane] * We2[lane];
    float pa = sesa[row * 128 + 64 + lane] * Wa2[lane];
    #pragma unroll
    for (int m = 1; m < 64; m <<= 1) {
      pe += __shfl_xor(pe, m, 64);
      pa += __shfl_xor(pa, m, 64);
    }
    if (lane == 0) {
      eta[row]   = sigmoid_f(pe + be2[0]) * 0.1f + 0.01f;
      alpha[row] = sigmoid_f(pa + ba2[0]) * 0.5f + 0.5f;
    }
  }
}

// ---- chunked scan (round-9 structure, measured best 42.7us): full dbuf
// staging, register prefetch one chunk ahead, 3 barriers/chunk, XCD remap,
// split accumulators. Added: s_setprio around MFMA clusters (T5).
__global__ __launch_bounds__(256, 1) void scan_chunk_k(
    const ushort* __restrict__ kb, const ushort* __restrict__ qb,
    const ushort* __restrict__ vhb, const ushort* __restrict__ Ktg,
    const ushort* __restrict__ Tg, const ushort* __restrict__ Gqg,
    const float* __restrict__ Sg,
    ushort* __restrict__ outb, float* __restrict__ Mout)
{
  __shared__ ushort K_lds[2][CCH * KSTR];
  __shared__ ushort Q_lds[2][CCH * KSTR];
  __shared__ ushort Kt_lds[2][F_ * KTSTR];
  __shared__ ushort M_lds[16 * KSTR];
  __shared__ ushort T_lds[2][CCH * TSTR];
  __shared__ ushort Gq_lds[2][CCH * TSTR];
  __shared__ ushort Wt_lds[16 * TSTR];
  __shared__ ushort R_lds[16 * TSTR];
  __shared__ float  QM_lds[CCH * 20];
  __shared__ ushort V_lds[2][CCH * 16];
  __shared__ float  scal[2][104];

  const int tid = threadIdx.x;
  const int flat = blockIdx.x;
  const int h = (flat & 7) + (((flat >> 3) >> 4) << 3);  // XCD-aware remap
  const int slice = (flat >> 3) & 15;
  const int r0 = slice * 16;
  const int wv = tid >> 6, l = tid & 63;
  const int ln = l & 15, hi = l >> 4, hi4 = hi << 2, hi8 = hi << 3;

  for (int u = tid; u < 16 * KSTR / 8; u += 256) {
    short8_t z = {0, 0, 0, 0, 0, 0, 0, 0};
    *(short8_t*)&M_lds[u * 8] = z;
  }
  f32x4 Mf[4];
  #pragma unroll
  for (int q = 0; q < 4; ++q)
    #pragma unroll
    for (int r = 0; r < 4; ++r) Mf[q][r] = 0.f;

  const ushort* kgh = kb + (size_t)h * S_ * F_;
  const ushort* qgh = qb + (size_t)h * S_ * F_;
  const ushort* kth = Ktg + (size_t)h * F_ * S_;

  short8_t pK[4], pQ[4], pKt[4], pTG;
  ushort pV[2]; float pS = 0.f;

  auto loadchunk = [&](int ch) {
    const int t0 = ch * CCH;
    #pragma unroll
    for (int r = 0; r < 4; ++r) {
      const int idx = (r << 8) + tid;
      const int t = idx >> 5, c8 = (idx & 31) << 3;
      pK[r] = *(const short8_t*)&kgh[(size_t)(t0 + t) * F_ + c8];
      pQ[r] = *(const short8_t*)&qgh[(size_t)(t0 + t) * F_ + c8];
    }
    #pragma unroll
    for (int r = 0; r < 4; ++r) {
      const int idx = (r << 8) + tid;
      const int c = idx >> 2, t8 = (idx & 3) << 3;
      pKt[r] = *(const short8_t*)&kth[(size_t)c * S_ + t0 + t8];
    }
    #pragma unroll
    for (int u = 0; u < 2; ++u) {
      const int e = (u << 8) + tid, t = e >> 4, i = e & 15;
      pV[u] = vhb[(size_t)(h * S_ + t0 + t) * F_ + r0 + i];
    }
    {
      const ushort* Ti = Tg  + (size_t)(h * NCH + ch) * (CCH * CCH);
      const ushort* Gi = Gqg + (size_t)(h * NCH + ch) * (CCH * CCH);
      if (tid < 128) {
        const int t = tid >> 2, c8 = (tid & 3) << 3;
        pTG = *(const short8_t*)&Ti[t * CCH + c8];
      } else {
        const int t = (tid - 128) >> 2, c8 = ((tid - 128) & 3) << 3;
        pTG = *(const short8_t*)&Gi[t * CCH + c8];
      }
    }
    if (tid < 97) pS = Sg[(size_t)(h * NCH + ch) * 128 + tid];
  };

  auto commit = [&](int buf) {
    #pragma unroll
    for (int r = 0; r < 4; ++r) {
      const int idx = (r << 8) + tid;
      const int t = idx >> 5, c8 = (idx & 31) << 3;
      *(short8_t*)&K_lds[buf][t * KSTR + c8] = pK[r];
      *(short8_t*)&Q_lds[buf][t * KSTR + c8] = pQ[r];
    }
    #pragma unroll
    for (int r = 0; r < 4; ++r) {
      const int idx = (r << 8) + tid;
      const int c = idx >> 2, t8 = (idx & 3) << 3;
      *(short8_t*)&Kt_lds[buf][c * KTSTR + t8] = pKt[r];
    }
    #pragma unroll
    for (int u = 0; u < 2; ++u) V_lds[buf][(u << 8) + tid] = pV[u];
    if (tid < 128) {
      const int t = tid >> 2, c8 = (tid & 3) << 3;
      *(short8_t*)&T_lds[buf][t * TSTR + c8] = pTG;
    } else {
      const int t = (tid - 128) >> 2, c8 = ((tid - 128) & 3) << 3;
      *(short8_t*)&Gq_lds[buf][t * TSTR + c8] = pTG;
    }
    if (tid < 97) scal[buf][tid] = pS;
  };

  loadchunk(0);
  commit(0);
  __syncthreads();

  for (int ch = 0; ch < NCH; ++ch) {
    const int buf = ch & 1;
    const int t0 = ch * CCH;
    if (ch + 1 < NCH) loadchunk(ch + 1);

    // phase 2: KM->RHS (waves 0,1) || QM (waves 2,3) — split accumulators
    __builtin_amdgcn_s_setprio(1);
    if (wv < 2) {
      const int I = wv;
      f32x4 a0 = {0.f, 0.f, 0.f, 0.f}, a1 = {0.f, 0.f, 0.f, 0.f};
      #pragma unroll
      for (int ko = 0; ko < 4; ++ko) {
        {
          short8_t a = *(const short8_t*)&K_lds[buf][(I * 16 + ln) * KSTR + (2 * ko) * 32 + hi8];
          short8_t b = *(const short8_t*)&M_lds[ln * KSTR + (2 * ko) * 32 + hi8];
          a0 = __builtin_amdgcn_mfma_f32_16x16x32_bf16(a, b, a0, 0, 0, 0);
        }
        {
          short8_t a = *(const short8_t*)&K_lds[buf][(I * 16 + ln) * KSTR + (2 * ko + 1) * 32 + hi8];
          short8_t b = *(const short8_t*)&M_lds[ln * KSTR + (2 * ko + 1) * 32 + hi8];
          a1 = __builtin_amdgcn_mfma_f32_16x16x32_bf16(a, b, a1, 0, 0, 0);
        }
      }
      #pragma unroll
      for (int r = 0; r < 4; ++r) {
        const int t = I * 16 + hi4 + r;
        const float s = a0[r] + a1[r];
        const float rhs = scal[buf][CCH + t] * bf2f(V_lds[buf][t * 16 + ln])
                        - scal[buf][t] * s;
        R_lds[ln * TSTR + t] = f2bf(rhs);
      }
    } else {
      const int I = wv - 2;
      f32x4 a0 = {0.f, 0.f, 0.f, 0.f}, a1 = {0.f, 0.f, 0.f, 0.f};
      #pragma unroll
      for (int ko = 0; ko < 4; ++ko) {
        {
          short8_t a = *(const short8_t*)&Q_lds[buf][(I * 16 + ln) * KSTR + (2 * ko) * 32 + hi8];
          short8_t b = *(const short8_t*)&M_lds[ln * KSTR + (2 * ko) * 32 + hi8];
          a0 = __builtin_amdgcn_mfma_f32_16x16x32_bf16(a, b, a0, 0, 0, 0);
        }
        {
          short8_t a = *(const short8_t*)&Q_lds[buf][(I * 16 + ln) * KSTR + (2 * ko + 1) * 32 + hi8];
          short8_t b = *(const short8_t*)&M_lds[ln * KSTR + (2 * ko + 1) * 32 + hi8];
          a1 = __builtin_amdgcn_mfma_f32_16x16x32_bf16(a, b, a1, 0, 0, 0);
        }
      }
      #pragma unroll
      for (int r = 0; r < 4; ++r)
        QM_lds[(I * 16 + hi4 + r) * 20 + ln] = a0[r] + a1[r];
    }
    __builtin_amdgcn_s_setprio(0);
    __syncthreads();

    // phase 3: W = T @ RHS (waves 0,1), stored [c][t]
    if (wv < 2) {
      const int I = wv;
      short8_t a = *(const short8_t*)&T_lds[buf][(I * 16 + ln) * TSTR + hi8];
      short8_t b = *(const short8_t*)&R_lds[ln * TSTR + hi8];
      f32x4 z = {0.f, 0.f, 0.f, 0.f};
      f32x4 d = __builtin_amdgcn_mfma_f32_16x16x32_bf16(a, b, z, 0, 0, 0);
      #pragma unroll
      for (int r = 0; r < 4; ++r)
        Wt_lds[ln * TSTR + I * 16 + hi4 + r] = f2bf(d[r]);
    }
    __syncthreads();

    // phase 4: OUT (waves 0,1) || M update (all waves); commit next
    __builtin_amdgcn_s_setprio(1);
    if (wv < 2) {
      const int I = wv;
      short8_t a = *(const short8_t*)&Gq_lds[buf][(I * 16 + ln) * TSTR + hi8];
      short8_t b = *(const short8_t*)&Wt_lds[ln * TSTR + hi8];
      f32x4 z = {0.f, 0.f, 0.f, 0.f};
      f32x4 d = __builtin_amdgcn_mfma_f32_16x16x32_bf16(a, b, z, 0, 0, 0);
      #pragma unroll
      for (int r = 0; r < 4; ++r) {
        const int t = I * 16 + hi4 + r;
        outb[(size_t)(h * S_ + t0 + t) * F_ + r0 + ln] =
            f2bf(scal[buf][2 * CCH + t] * (QM_lds[t * 20 + ln] + d[r]));
      }
    }
    {
      const float gC = scal[buf][3 * CCH];
      short8_t aw = *(const short8_t*)&Wt_lds[ln * TSTR + hi8];
      #pragma unroll
      for (int qq = 0; qq < 4; ++qq) {
        const int jt = wv * 4 + qq;
        short8_t bk = *(const short8_t*)&Kt_lds[buf][(jt * 16 + ln) * KTSTR + hi8];
        f32x4 d = __builtin_amdgcn_mfma_f32_16x16x32_bf16(aw, bk, Mf[qq], 0, 0, 0);
        #pragma unroll
        for (int r = 0; r < 4; ++r) {
          const float nv = gC * d[r];
          Mf[qq][r] = nv;
          M_lds[(hi4 + r) * KSTR + jt * 16 + ln] = f2bf(nv);
        }
      }
    }
    __builtin_amdgcn_s_setprio(0);
    if (ch + 1 < NCH) commit(buf ^ 1);
    __syncthreads();
  }

  #pragma unroll
  for (int qq = 0; qq < 4; ++qq) {
    const int jt = wv * 4 + qq;
    #pragma unroll
    for (int r = 0; r < 4; ++r)
      Mout[((size_t)h * F_ + r0 + hi4 + r) * F_ + jt * 16 + ln] = Mf[qq][r];
  }
}

extern "C" void kernel_launch(void* const* d_in, const int* in_sizes, int n_in,
                              void* d_out, int out_size, void* d_ws, size_t ws_size,
                              hipStream_t stream)
{
  const float* x    = (const float*)d_in[0];
  const float* Wq   = (const float*)d_in[1];
  const float* Wk   = (const float*)d_in[2];
  const float* Wv   = (const float*)d_in[3];
  const float* Wg1  = (const float*)d_in[4];
  const float* bg1  = (const float*)d_in[5];
  const float* Wg2  = (const float*)d_in[6];
  const float* bg2  = (const float*)d_in[7];
  const float* We1  = (const float*)d_in[8];
  const float* be1  = (const float*)d_in[9];
  const float* We2  = (const float*)d_in[10];
  const float* be2  = (const float*)d_in[11];
  const float* Wa1  = (const float*)d_in[12];
  const float* ba1  = (const float*)d_in[13];
  const float* Wa2  = (const float*)d_in[14];
  const float* ba2  = (const float*)d_in[15];
  const float* Wo   = (const float*)d_in[16];
  const float* bo   = (const float*)d_in[17];
  const float* gamma= (const float*)d_in[18];
  const float* beta = (const float*)d_in[19];

  const int Mrows = NH_ * S_;               // 8192
  const size_t MM = 1048576;                // 1M floats
  const size_t NTF = 2 * MM;

  float* ws = (float*)d_ws;
  ushort* outb = (ushort*)(ws + 0 * MM);   // scan output (bf16)
  ushort* qb   = (ushort*)(ws + 1 * MM);
  ushort* kb   = (ushort*)(ws + 2 * MM);
  float*  kf   = ws + 3 * MM;              // f32 [3M,5M); dead after knea
  ushort* t1b  = (ushort*)(ws + 3 * MM);   // reuse after knea
  ushort* vhb  = (ushort*)(ws + 4 * MM);   // bf16 v_hat
  ushort* vb   = (ushort*)(ws + 5 * MM);   // bf16 v; dead after g1 gemm
  float*  sesa = ws + 6 * MM;              // f32 [6M,7M); dead after knea
  float*  eta  = ws + 7 * MM;
  float*  alpha= eta + Mrows;
  ushort* Tg   = (ushort*)(ws + 7 * MM + 16384);
  ushort* Gqg  = Tg + 262144;
  float*  Sg   = ws + 7 * MM + 16384 + 131072 + 131072;
  ushort* Ktg  = (ushort*)(Sg + 32768);
  ushort* Wt   = Ktg + 2097152;
  float*  beas = (float*)(Wt + 425984);

  dim3 blk(256);

  wconv_k<<<105, blk, 0, stream>>>(Wq, Wk, Wv, Wg1, Wg2, Wo, We1, Wa1,
                                   be1, ba1, Wt, beas);

  qkve_k<<<dim3(14, 128), blk, 0, stream>>>(x, Wt, beas, qb, kf, vb, sesa);

  knea_k<<<Mrows / 4, blk, 0, stream>>>(kf, kb, sesa, We2, be2, Wa2, ba2, eta, alpha);

  // fused: g1 GEMM (blocks 0..511) + prep (blocks 512..767)
  g1prep_k<<<768, blk, 0, stream>>>(vb, Wt + 229376, bg1, t1b,
                                    kb, qb, eta, alpha, Tg, Gqg, Sg, Ktg);

  gemm_bf16_k<<<dim3(4, 128), blk, 0, stream>>>(t1b, Wt + 294912, bg2, nullptr, vhb, 0);

  float* yout = (float*)d_out;
  float* Mfin = yout + NTF;
  scan_chunk_k<<<256, blk, 0, stream>>>(kb, qb, vhb, Ktg, Tg, Gqg, Sg, outb, Mfin);

  gemmo_ln_k<<<256, blk, 0, stream>>>(outb, Wt + 360448, bo, x, gamma, beta, yout);
}